// Round 8
// baseline (80.818 us; speedup 1.0000x reference)
//
#include <hip/hip_runtime.h>

typedef _Float16 f16;
typedef __attribute__((ext_vector_type(8))) _Float16 f16x8;
typedef __attribute__((ext_vector_type(4))) _Float16 f16x4;
typedef __attribute__((ext_vector_type(4))) float f32x4;

#define NB 16
#define LSEQ 2048
#define DIM 64
#define KVB 64
#define QT 64
#define NT (LSEQ / KVB)
#define PITCH 72  // f16/row (144B): 16B-aligned, rotates bank groups by 4/row
#define LOG2E 1.44269504088896340736f

// ---------- pre-kernel 1: bucket-sort queries by needed tile count (descending) ----------
__global__ void build_perm(const int* __restrict__ vlg, int* __restrict__ perm) {
    const int b = blockIdx.x, tid = threadIdx.x;
    __shared__ int hist[NT + 1];
    __shared__ int base[NT + 1];
    if (tid <= NT) hist[tid] = 0;
    __syncthreads();
    for (int q = tid; q < LSEQ; q += 256) {
        int vl = vlg[b * LSEQ + q];
        int t = (vl == 0) ? 0 : ((vl + KVB - 1) >> 6);
        atomicAdd(&hist[t], 1);
    }
    __syncthreads();
    if (tid == 0) {            // descending bucket order: heavy queries first
        int acc = 0;
        for (int t = NT; t >= 0; --t) { base[t] = acc; acc += hist[t]; }
    }
    __syncthreads();
    for (int q = tid; q < LSEQ; q += 256) {
        int vl = vlg[b * LSEQ + q];
        int t = (vl == 0) ? 0 : ((vl + KVB - 1) >> 6);
        int pos = atomicAdd(&base[t], 1);
        perm[b * LSEQ + pos] = q;
    }
}

// ---------- pre-kernel 2: per-batch column mean of V (for vl==0 queries) ----------
__global__ void vmean_k(const float* __restrict__ vg, float* __restrict__ vmean) {
    const int b = blockIdx.x, tid = threadIdx.x;
    const int col = tid & 63, part = tid >> 6;  // 4 parts x 512 rows
    const float* vb = vg + (size_t)b * LSEQ * DIM;
    float s = 0.f;
    for (int i = 0; i < LSEQ / 4; ++i)
        s += vb[(size_t)(part * (LSEQ / 4) + i) * DIM + col];
    __shared__ float ps[4][64];
    ps[part][col] = s;
    __syncthreads();
    if (tid < 64)
        vmean[b * DIM + tid] = (ps[0][tid] + ps[1][tid] + ps[2][tid] + ps[3][tid]) * (1.0f / LSEQ);
}

// ---------- main attention kernel ----------
__global__ __launch_bounds__(256, 2) void attn_fwd(
    const float* __restrict__ qg, const float* __restrict__ kg,
    const float* __restrict__ vg, const int* __restrict__ vlg,
    float* __restrict__ outg, const int* __restrict__ perm,
    const float* __restrict__ vmeang, int sorted)
{
    __shared__ alignas(16) f16 kld[2][KVB * PITCH];   // K[key][d], double-buffered
    __shared__ alignas(16) f16 vtld[2][DIM * PITCH];  // V^T[dv][key], double-buffered
    __shared__ alignas(16) f16 pld[4 * 16 * PITCH];   // per-wave P[q][key]
    __shared__ int wmax[4];

    const int tid  = threadIdx.x;
    const int wid  = tid >> 6;
    const int lane = tid & 63;
    const int r    = lane & 15;
    const int hi   = lane >> 4;

    // XCD-aware swizzle: 512 blocks, 8 XCDs -> 2 batches per XCD (K+V=2MB fits 4MB L2)
    const int bid = blockIdx.x;
    const int xcd = bid & 7;
    const int idx = bid >> 3;
    const int b   = xcd * 2 + (idx >> 5);
    const int qt  = idx & 31;
    const int qw  = qt * QT + wid * 16;

    const int kb  = tid & 15;   // V staging: key block (4 keys)
    const int dvb = tid >> 4;   // V staging: dv block (4 dv)

    // this lane's query (sorted permutation or identity)
    const int qidx = sorted ? perm[b * LSEQ + qw + r] : (qw + r);
    const int vl   = vlg[b * LSEQ + qidx];

    // per-block tile bound: max needed tiles over the block's 64 queries
    int maxt;
    if (sorted) {
        int tq = (vl == 0) ? 0 : ((vl + KVB - 1) >> 6);
        tq = max(tq, __shfl_xor(tq, 1));
        tq = max(tq, __shfl_xor(tq, 2));
        tq = max(tq, __shfl_xor(tq, 4));
        tq = max(tq, __shfl_xor(tq, 8));
        if (lane == 0) wmax[wid] = tq;
        __syncthreads();
        maxt = max(max(wmax[0], wmax[1]), max(wmax[2], wmax[3]));
    } else {
        maxt = NT;   // fallback: vl==0 handled naturally by full processing
    }

    // ---- Q fragments (f32*LOG2E -> f16): B-operand for mfma(K, Q); lane holds q-col r ----
    f16x8 qf[2];
    const float* qrow = qg + ((size_t)(b * LSEQ + qidx)) * DIM;
#pragma unroll
    for (int ks = 0; ks < 2; ++ks) {
        f32x4 x = *(const f32x4*)(qrow + ks * 32 + hi * 8);
        f32x4 y = *(const f32x4*)(qrow + ks * 32 + hi * 8 + 4);
        f16x8 t;
        t[0]=(f16)(x[0]*LOG2E); t[1]=(f16)(x[1]*LOG2E); t[2]=(f16)(x[2]*LOG2E); t[3]=(f16)(x[3]*LOG2E);
        t[4]=(f16)(y[0]*LOG2E); t[5]=(f16)(y[1]*LOG2E); t[6]=(f16)(y[2]*LOG2E); t[7]=(f16)(y[3]*LOG2E);
        qf[ks] = t;
    }

    float m_run = -INFINITY;   // log2-domain running max
    float l_run = 0.0f;
    f32x4 o[4];
#pragma unroll
    for (int dt = 0; dt < 4; ++dt) o[dt] = f32x4{0.f, 0.f, 0.f, 0.f};

    f16* pw = pld + wid * (16 * PITCH);
    const float* kbase = kg + ((size_t)b * LSEQ) * DIM;
    const float* vbase = vg + ((size_t)b * LSEQ) * DIM;

    f32x4 kst[4], vst[4];

    if (maxt > 0) {
        // ---- prologue: load tile 0 -> regs, convert+write -> buf 0 ----
#pragma unroll
        for (int it = 0; it < 4; ++it) {
            int cc = tid + it * 256;
            kst[it] = *(const f32x4*)(kbase + (size_t)(cc >> 4) * DIM + (cc & 15) * 4);
        }
#pragma unroll
        for (int i = 0; i < 4; ++i)
            vst[i] = *(const f32x4*)(vbase + (size_t)(kb * 4 + i) * DIM + dvb * 4);
#pragma unroll
        for (int it = 0; it < 4; ++it) {
            int cc = tid + it * 256;
            f16x4 t;
            t[0]=(f16)kst[it][0]; t[1]=(f16)kst[it][1]; t[2]=(f16)kst[it][2]; t[3]=(f16)kst[it][3];
            *(f16x4*)(&kld[0][(cc >> 4) * PITCH + (cc & 15) * 4]) = t;
        }
#pragma unroll
        for (int j = 0; j < 4; ++j) {
            f16x4 t;
            t[0]=(f16)vst[0][j]; t[1]=(f16)vst[1][j]; t[2]=(f16)vst[2][j]; t[3]=(f16)vst[3][j];
            *(f16x4*)(&vtld[0][(dvb * 4 + j) * PITCH + kb * 4]) = t;
        }
    }

    int c = 0;
    for (int t = 0; t < maxt; ++t) {
        __syncthreads();  // buf[c] staged & prior reads of buf[c^1] done

        // ---- issue next tile's global loads (latency hides under compute) ----
        if (t + 1 < maxt) {
            int kv0 = (t + 1) * KVB;
#pragma unroll
            for (int it = 0; it < 4; ++it) {
                int cc = tid + it * 256;
                kst[it] = *(const f32x4*)(kbase + (size_t)(kv0 + (cc >> 4)) * DIM + (cc & 15) * 4);
            }
#pragma unroll
            for (int i = 0; i < 4; ++i)
                vst[i] = *(const f32x4*)(vbase + (size_t)(kv0 + kb * 4 + i) * DIM + dvb * 4);
        }

        // ---- S^T = mfma(K, Q): lane holds query col r, key rows kt*16 + 4*hi + g ----
        f32x4 st[4];
        __builtin_amdgcn_s_setprio(1);
#pragma unroll
        for (int kt = 0; kt < 4; ++kt) {
            f32x4 acc = f32x4{0.f, 0.f, 0.f, 0.f};
#pragma unroll
            for (int ks = 0; ks < 2; ++ks) {
                f16x8 kf = *(const f16x8*)(&kld[c][(kt * 16 + r) * PITCH + ks * 32 + hi * 8]);
                acc = __builtin_amdgcn_mfma_f32_16x16x32_f16(kf, qf[ks], acc, 0, 0, 0);
            }
            st[kt] = acc;
        }
        __builtin_amdgcn_s_setprio(0);

        // ---- mask + online softmax (scores already in log2 domain via Q*LOG2E) ----
        const int kv0 = t * KVB;
        float tmax = -INFINITY;
#pragma unroll
        for (int kt = 0; kt < 4; ++kt)
#pragma unroll
            for (int g = 0; g < 4; ++g) {
                int key = kv0 + kt * 16 + hi * 4 + g;
                float s = (key < vl) ? st[kt][g] : -1e9f;
                st[kt][g] = s;
                tmax = fmaxf(tmax, s);
            }
        tmax = fmaxf(tmax, __shfl_xor(tmax, 16));
        tmax = fmaxf(tmax, __shfl_xor(tmax, 32));
        float m_new = fmaxf(m_run, tmax);
        float scale = exp2f(m_run - m_new);  // first tile: exp2(-inf)=0
        float tsum = 0.0f;
#pragma unroll
        for (int kt = 0; kt < 4; ++kt) {
            f16x4 pv;
#pragma unroll
            for (int g = 0; g < 4; ++g) {
                float p = exp2f(st[kt][g] - m_new);
                tsum += p;
                pv[g] = (f16)p;
            }
            *(f16x4*)(pw + r * PITCH + kt * 16 + hi * 4) = pv;  // P[q=r][key]
        }
        tsum += __shfl_xor(tsum, 16);
        tsum += __shfl_xor(tsum, 32);
        l_run = l_run * scale + tsum;
        m_run = m_new;

        // ---- rescale O (O cols g are queries 4*hi+g; state lives in lane 4*hi+g) ----
#pragma unroll
        for (int g = 0; g < 4; ++g) {
            float sc = __shfl(scale, hi * 4 + g);
#pragma unroll
            for (int dt = 0; dt < 4; ++dt) o[dt][g] *= sc;
        }

        // ---- PV: O += mfma(P, V); wave-private P round-trip (lgkmcnt only) ----
        __builtin_amdgcn_s_setprio(1);
#pragma unroll
        for (int ks = 0; ks < 2; ++ks) {
            f16x8 pa = *(const f16x8*)(pw + r * PITCH + ks * 32 + hi * 8);
#pragma unroll
            for (int dt = 0; dt < 4; ++dt) {
                f16x8 vf = *(const f16x8*)(&vtld[c][(dt * 16 + r) * PITCH + ks * 32 + hi * 8]);
                o[dt] = __builtin_amdgcn_mfma_f32_16x16x32_f16(pa, vf, o[dt], 0, 0, 0);
            }
        }
        __builtin_amdgcn_s_setprio(0);

        // ---- convert + write next tile into buf[c^1] ----
        if (t + 1 < maxt) {
#pragma unroll
            for (int it = 0; it < 4; ++it) {
                int cc = tid + it * 256;
                f16x4 tt;
                tt[0]=(f16)kst[it][0]; tt[1]=(f16)kst[it][1]; tt[2]=(f16)kst[it][2]; tt[3]=(f16)kst[it][3];
                *(f16x4*)(&kld[c ^ 1][(cc >> 4) * PITCH + (cc & 15) * 4]) = tt;
            }
#pragma unroll
            for (int j = 0; j < 4; ++j) {
                f16x4 tt;
                tt[0]=(f16)vst[0][j]; tt[1]=(f16)vst[1][j]; tt[2]=(f16)vst[2][j]; tt[3]=(f16)vst[3][j];
                *(f16x4*)(&vtld[c ^ 1][(dvb * 4 + j) * PITCH + kb * 4]) = tt;
            }
        }
        c ^= 1;
    }

    // ---- epilogue: divide by denom (or vl==0 -> colmean(V)), scatter-store f32 ----
    float inv = 1.0f / l_run;
#pragma unroll
    for (int g = 0; g < 4; ++g) {
        float iv = __shfl(inv, hi * 4 + g);
        int   qo = __shfl(qidx, hi * 4 + g);
        int   vq = __shfl(vl,   hi * 4 + g);
        float* ob = outg + ((size_t)(b * LSEQ + qo)) * DIM;
#pragma unroll
        for (int dt = 0; dt < 4; ++dt) {
            float val = o[dt][g] * iv;
            if (sorted && vq == 0) val = vmeang[b * DIM + dt * 16 + r];
            ob[dt * 16 + r] = val;
        }
    }
}

extern "C" void kernel_launch(void* const* d_in, const int* in_sizes, int n_in,
                              void* d_out, int out_size, void* d_ws, size_t ws_size,
                              hipStream_t stream) {
    const float* q  = (const float*)d_in[0];
    const float* k  = (const float*)d_in[1];
    const float* v  = (const float*)d_in[2];
    const int*   vl = (const int*)d_in[3];
    float* out = (float*)d_out;

    const size_t perm_bytes  = (size_t)NB * LSEQ * sizeof(int);
    const size_t vmean_bytes = (size_t)NB * DIM * sizeof(float);
    const bool sorted = (ws_size >= perm_bytes + vmean_bytes) && d_ws != nullptr;

    int*   perm  = (int*)d_ws;
    float* vmean = (float*)((char*)d_ws + perm_bytes);

    if (sorted) {
        build_perm<<<NB, 256, 0, stream>>>(vl, perm);
        vmean_k<<<NB, 256, 0, stream>>>(v, vmean);
    }
    attn_fwd<<<NB * (LSEQ / QT), 256, 0, stream>>>(q, k, v, vl, out,
                                                   perm, vmean, (int)sorted);
}

// Round 11
// 54.150 us; speedup vs baseline: 1.4925x; 1.4925x over previous
//
#include <hip/hip_runtime.h>

typedef _Float16 f16;
typedef __attribute__((ext_vector_type(8))) _Float16 f16x8;
typedef __attribute__((ext_vector_type(4))) _Float16 f16x4;
typedef __attribute__((ext_vector_type(4))) float f32x4;

#define NB 16
#define LSEQ 2048
#define DIM 64
#define KVB 64
#define QT 64
#define NT (LSEQ / KVB)
#define PITCH 72  // f16/row (144B): 16B-aligned, conflict-free b128 reads
#define LOG2E 1.44269504088896340736f

__device__ inline f16x4 pkcvt(const f32x4 x) {
    auto a = __builtin_amdgcn_cvt_pkrtz(x[0], x[1]);   // __fp16 x2
    auto b = __builtin_amdgcn_cvt_pkrtz(x[2], x[3]);
    f16x4 t; t[0]=(f16)a[0]; t[1]=(f16)a[1]; t[2]=(f16)b[0]; t[3]=(f16)b[1];
    return t;
}

// ---- pre-kernel: bucket-sort queries by tile count (desc); vl==0 -> NT (full pass = exact mean) ----
__global__ void build_perm(const int* __restrict__ vlg, int* __restrict__ perm) {
    const int b = blockIdx.x, tid = threadIdx.x;
    __shared__ int hist[NT + 1];
    __shared__ int base[NT + 1];
    if (tid <= NT) hist[tid] = 0;
    __syncthreads();
    for (int q = tid; q < LSEQ; q += 256) {
        int vl = vlg[b * LSEQ + q];
        int t = (vl == 0) ? NT : ((vl + KVB - 1) >> 6);
        atomicAdd(&hist[t], 1);
    }
    __syncthreads();
    if (tid == 0) {
        int acc = 0;
        for (int t = NT; t >= 0; --t) { base[t] = acc; acc += hist[t]; }
    }
    __syncthreads();
    for (int q = tid; q < LSEQ; q += 256) {
        int vl = vlg[b * LSEQ + q];
        int t = (vl == 0) ? NT : ((vl + KVB - 1) >> 6);
        int pos = atomicAdd(&base[t], 1);
        perm[b * LSEQ + pos] = q;
    }
}

// ---- main attention kernel: tasks = (qt, b, split); round-robin tiles per split ----
__global__ __launch_bounds__(256, 3) void attn_fwd(
    const float* __restrict__ qg, const float* __restrict__ kg,
    const float* __restrict__ vg, const int* __restrict__ vlg,
    float* __restrict__ outg, const int* __restrict__ perm,
    float* __restrict__ opart, float* __restrict__ mlg,
    int sorted, int S)
{
    __shared__ alignas(16) f16 kld[2][KVB * PITCH];   // K[key][d], dbuf
    __shared__ alignas(16) f16 vtld[2][DIM * PITCH];  // V^T[dv][key], dbuf
    __shared__ alignas(16) f16 pld[4 * 16 * PITCH];   // per-wave P[q][key]
    __shared__ int wmax[4];

    const int tid  = threadIdx.x;
    const int wid  = tid >> 6;
    const int lane = tid & 63;
    const int r    = lane & 15;
    const int hi   = lane >> 4;

    // qt-major bid order: heavy tasks (low qt, sorted desc) dispatch first -> backfill balance
    const int bid = blockIdx.x;
    const int nbs = NB * S;
    const int qt  = bid / nbs;
    const int rem = bid - qt * nbs;
    const int b   = rem / S;
    const int s   = rem - b * S;
    const int qw  = qt * QT + wid * 16;

    const int kb  = tid & 15;   // V staging: key block
    const int dvb = tid >> 4;   // V staging: dv block

    const int qidx = sorted ? perm[b * LSEQ + qw + r] : (qw + r);
    const int vl   = vlg[b * LSEQ + qidx];

    // block tile bound
    int maxt;
    if (sorted) {
        int tq = (vl == 0) ? NT : ((vl + KVB - 1) >> 6);
        tq = max(tq, __shfl_xor(tq, 1));
        tq = max(tq, __shfl_xor(tq, 2));
        tq = max(tq, __shfl_xor(tq, 4));
        tq = max(tq, __shfl_xor(tq, 8));
        if (lane == 0) wmax[wid] = tq;
        __syncthreads();
        maxt = max(max(wmax[0], wmax[1]), max(wmax[2], wmax[3]));
    } else {
        maxt = NT;
    }

    // wave-min vl: tiles fully valid for whole wave skip the mask pass
    int vmin = vl;
    vmin = min(vmin, __shfl_xor(vmin, 1));
    vmin = min(vmin, __shfl_xor(vmin, 2));
    vmin = min(vmin, __shfl_xor(vmin, 4));
    vmin = min(vmin, __shfl_xor(vmin, 8));

    // ---- Q fragments (f32*LOG2E -> f16) ----
    f16x8 qf[2];
    const float* qrow = qg + ((size_t)(b * LSEQ + qidx)) * DIM;
#pragma unroll
    for (int ks = 0; ks < 2; ++ks) {
        f32x4 x = *(const f32x4*)(qrow + ks * 32 + hi * 8);
        f32x4 y = *(const f32x4*)(qrow + ks * 32 + hi * 8 + 4);
        f32x4 xs = {x[0]*LOG2E, x[1]*LOG2E, x[2]*LOG2E, x[3]*LOG2E};
        f32x4 ys = {y[0]*LOG2E, y[1]*LOG2E, y[2]*LOG2E, y[3]*LOG2E};
        f16x4 lo = pkcvt(xs), hi4 = pkcvt(ys);
        f16x8 t;
        t[0]=lo[0]; t[1]=lo[1]; t[2]=lo[2]; t[3]=lo[3];
        t[4]=hi4[0]; t[5]=hi4[1]; t[6]=hi4[2]; t[7]=hi4[3];
        qf[ks] = t;
    }

    float m_run = -INFINITY;
    float l_run = 0.0f;
    f32x4 o[4];
#pragma unroll
    for (int dt = 0; dt < 4; ++dt) o[dt] = f32x4{0.f, 0.f, 0.f, 0.f};

    f16* pw = pld + wid * (16 * PITCH);
    const float* kbase = kg + ((size_t)b * LSEQ) * DIM;
    const float* vbase = vg + ((size_t)b * LSEQ) * DIM;

    f32x4 kst[4], vst[4];

    if (s < maxt) {
        // prologue: stage tile s into buf 0
        const int kv0 = s * KVB;
#pragma unroll
        for (int it = 0; it < 4; ++it) {
            int cc = tid + it * 256;
            kst[it] = *(const f32x4*)(kbase + (size_t)(kv0 + (cc >> 4)) * DIM + (cc & 15) * 4);
        }
#pragma unroll
        for (int i = 0; i < 4; ++i)
            vst[i] = *(const f32x4*)(vbase + (size_t)(kv0 + kb * 4 + i) * DIM + dvb * 4);
#pragma unroll
        for (int it = 0; it < 4; ++it) {
            int cc = tid + it * 256;
            *(f16x4*)(&kld[0][(cc >> 4) * PITCH + (cc & 15) * 4]) = pkcvt(kst[it]);
        }
#pragma unroll
        for (int j = 0; j < 4; ++j) {
            f32x4 col = {vst[0][j], vst[1][j], vst[2][j], vst[3][j]};
            *(f16x4*)(&vtld[0][(dvb * 4 + j) * PITCH + kb * 4]) = pkcvt(col);
        }
    }

    int c = 0;
    for (int tt = s; tt < maxt; tt += S) {
        __syncthreads();

        const int nt_ = tt + S;
        if (nt_ < maxt) {
            const int kv0n = nt_ * KVB;
#pragma unroll
            for (int it = 0; it < 4; ++it) {
                int cc = tid + it * 256;
                kst[it] = *(const f32x4*)(kbase + (size_t)(kv0n + (cc >> 4)) * DIM + (cc & 15) * 4);
            }
#pragma unroll
            for (int i = 0; i < 4; ++i)
                vst[i] = *(const f32x4*)(vbase + (size_t)(kv0n + kb * 4 + i) * DIM + dvb * 4);
        }

        // ---- S^T = mfma(K, Q) ----
        f32x4 st[4];
        __builtin_amdgcn_s_setprio(1);
#pragma unroll
        for (int kt = 0; kt < 4; ++kt) {
            f32x4 acc = f32x4{0.f, 0.f, 0.f, 0.f};
#pragma unroll
            for (int ks = 0; ks < 2; ++ks) {
                f16x8 kf = *(const f16x8*)(&kld[c][(kt * 16 + r) * PITCH + ks * 32 + hi * 8]);
                acc = __builtin_amdgcn_mfma_f32_16x16x32_f16(kf, qf[ks], acc, 0, 0, 0);
            }
            st[kt] = acc;
        }
        __builtin_amdgcn_s_setprio(0);

        // ---- mask + online softmax (log2 domain) ----
        const int kv0 = tt * KVB;
        float tmax = -INFINITY;
        if (kv0 + KVB > vmin) {
#pragma unroll
            for (int kt = 0; kt < 4; ++kt)
#pragma unroll
                for (int g = 0; g < 4; ++g) {
                    int key = kv0 + kt * 16 + hi * 4 + g;
                    float sc = (key < vl) ? st[kt][g] : -1e9f;
                    st[kt][g] = sc;
                    tmax = fmaxf(tmax, sc);
                }
        } else {
#pragma unroll
            for (int kt = 0; kt < 4; ++kt)
#pragma unroll
                for (int g = 0; g < 4; ++g)
                    tmax = fmaxf(tmax, st[kt][g]);
        }
        tmax = fmaxf(tmax, __shfl_xor(tmax, 16));
        tmax = fmaxf(tmax, __shfl_xor(tmax, 32));
        float m_new = fmaxf(m_run, tmax);
        float scale = exp2f(m_run - m_new);
        float tsum = 0.0f;
#pragma unroll
        for (int kt = 0; kt < 4; ++kt) {
            f16x4 pv;
#pragma unroll
            for (int g = 0; g < 4; ++g) {
                float p = exp2f(st[kt][g] - m_new);
                tsum += p;
                pv[g] = (f16)p;
            }
            *(f16x4*)(pw + r * PITCH + kt * 16 + hi * 4) = pv;
        }
        tsum += __shfl_xor(tsum, 16);
        tsum += __shfl_xor(tsum, 32);
        l_run = l_run * scale + tsum;
        m_run = m_new;

#pragma unroll
        for (int g = 0; g < 4; ++g) {
            float sc = __shfl(scale, hi * 4 + g);
#pragma unroll
            for (int dt = 0; dt < 4; ++dt) o[dt][g] *= sc;
        }

        // ---- PV ----
        __builtin_amdgcn_s_setprio(1);
#pragma unroll
        for (int ks = 0; ks < 2; ++ks) {
            f16x8 pa = *(const f16x8*)(pw + r * PITCH + ks * 32 + hi * 8);
#pragma unroll
            for (int dt = 0; dt < 4; ++dt) {
                f16x8 vf = *(const f16x8*)(&vtld[c][(dt * 16 + r) * PITCH + ks * 32 + hi * 8]);
                o[dt] = __builtin_amdgcn_mfma_f32_16x16x32_f16(pa, vf, o[dt], 0, 0, 0);
            }
        }
        __builtin_amdgcn_s_setprio(0);

        if (nt_ < maxt) {
#pragma unroll
            for (int it = 0; it < 4; ++it) {
                int cc = tid + it * 256;
                *(f16x4*)(&kld[c ^ 1][(cc >> 4) * PITCH + (cc & 15) * 4]) = pkcvt(kst[it]);
            }
#pragma unroll
            for (int j = 0; j < 4; ++j) {
                f32x4 col = {vst[0][j], vst[1][j], vst[2][j], vst[3][j]};
                *(f16x4*)(&vtld[c ^ 1][(dvb * 4 + j) * PITCH + kb * 4]) = pkcvt(col);
            }
        }
        c ^= 1;
    }

    // ---- epilogue ----
    if (S == 1) {
        float inv = 1.0f / l_run;
#pragma unroll
        for (int g = 0; g < 4; ++g) {
            float iv = __shfl(inv, hi * 4 + g);
            int   qo = __shfl(qidx, hi * 4 + g);
            float* ob = outg + ((size_t)(b * LSEQ + qo)) * DIM;
#pragma unroll
            for (int dt = 0; dt < 4; ++dt)
                ob[dt * 16 + r] = o[dt][g] * iv;
        }
    } else {
        float* obase = opart + ((size_t)s * NB * LSEQ + (size_t)b * LSEQ) * DIM;
#pragma unroll
        for (int g = 0; g < 4; ++g) {
            int qo = __shfl(qidx, hi * 4 + g);
            float* ob = obase + (size_t)qo * DIM;
#pragma unroll
            for (int dt = 0; dt < 4; ++dt)
                ob[dt * 16 + r] = o[dt][g];
        }
        if (hi == 0) {
            size_t mi = ((size_t)s * NB * LSEQ + (size_t)b * LSEQ + qidx) * 2;
            mlg[mi]     = m_run;
            mlg[mi + 1] = l_run;
        }
    }
}

// ---- merge kernel: combine S online-softmax partials exactly ----
__global__ void merge_k(const float* __restrict__ opart, const float* __restrict__ mlg,
                        float* __restrict__ outg, int S)
{
    const int gt = blockIdx.x * 256 + threadIdx.x;
    const size_t base = (size_t)gt * 4;
    const size_t qg = base >> 6;   // global query index (b*LSEQ+q)
    float M = -INFINITY;
    for (int s = 0; s < S; ++s)
        M = fmaxf(M, mlg[((size_t)s * NB * LSEQ + qg) * 2]);
    float den = 0.f;
    f32x4 acc = {0.f, 0.f, 0.f, 0.f};
    for (int s = 0; s < S; ++s) {
        size_t mi = ((size_t)s * NB * LSEQ + qg) * 2;
        float w = exp2f(mlg[mi] - M);   // fully-masked/empty splits -> w=0
        den += w * mlg[mi + 1];
        f32x4 ov = *(const f32x4*)(opart + (size_t)s * NB * LSEQ * DIM + base);
        acc[0] += w * ov[0]; acc[1] += w * ov[1];
        acc[2] += w * ov[2]; acc[3] += w * ov[3];
    }
    float inv = 1.0f / den;
    f32x4 res = {acc[0]*inv, acc[1]*inv, acc[2]*inv, acc[3]*inv};
    *(f32x4*)(outg + base) = res;
}

extern "C" void kernel_launch(void* const* d_in, const int* in_sizes, int n_in,
                              void* d_out, int out_size, void* d_ws, size_t ws_size,
                              hipStream_t stream) {
    const float* q  = (const float*)d_in[0];
    const float* k  = (const float*)d_in[1];
    const float* v  = (const float*)d_in[2];
    const int*   vl = (const int*)d_in[3];
    float* out = (float*)d_out;

    const size_t perm_b = (size_t)NB * LSEQ * sizeof(int);            // 128 KB
    auto need = [&](int S) {
        return perm_b + (size_t)S * NB * LSEQ * DIM * sizeof(float)   // o partials
                      + (size_t)S * NB * LSEQ * 2 * sizeof(float);    // m,l
    };
    int S, sorted;
    if      (d_ws && ws_size >= need(4)) { S = 4; sorted = 1; }
    else if (d_ws && ws_size >= need(2)) { S = 2; sorted = 1; }
    else if (d_ws && ws_size >= perm_b)  { S = 1; sorted = 1; }
    else                                 { S = 1; sorted = 0; }

    int*   perm  = (int*)d_ws;
    float* opart = (float*)((char*)d_ws + perm_b);
    float* mlg   = opart + (size_t)S * NB * LSEQ * DIM;

    if (sorted) build_perm<<<NB, 256, 0, stream>>>(vl, perm);

    attn_fwd<<<dim3(NB * (LSEQ / QT) * S), dim3(256), 0, stream>>>(
        q, k, v, vl, out, perm, opart, mlg, sorted, S);

    if (S > 1) {
        const int mthreads = NB * LSEQ * DIM / 4;   // 524288
        merge_k<<<dim3(mthreads / 256), dim3(256), 0, stream>>>(opart, mlg, out, S);
    }
}

// Round 12
// 51.930 us; speedup vs baseline: 1.5563x; 1.0427x over previous
//
#include <hip/hip_runtime.h>

typedef _Float16 f16;
typedef __attribute__((ext_vector_type(8))) _Float16 f16x8;
typedef __attribute__((ext_vector_type(4))) _Float16 f16x4;
typedef __attribute__((ext_vector_type(4))) float f32x4;

#define NB 16
#define LSEQ 2048
#define DIM 64
#define KVB 64
#define QT 64
#define NT (LSEQ / KVB)
#define PITCH 72           // P-buffer pitch (f16): 16B-aligned, spreads banks
#define LOG2E 1.44269504088896340736f

__device__ inline f16x4 pkcvt(const f32x4 x) {
    auto a = __builtin_amdgcn_cvt_pkrtz(x[0], x[1]);
    auto b = __builtin_amdgcn_cvt_pkrtz(x[2], x[3]);
    f16x4 t; t[0]=(f16)a[0]; t[1]=(f16)a[1]; t[2]=(f16)b[0]; t[3]=(f16)b[1];
    return t;
}

__device__ inline void gload16(const void* g, void* l) {
    __builtin_amdgcn_global_load_lds(
        (const __attribute__((address_space(1))) unsigned int*)g,
        (__attribute__((address_space(3))) unsigned int*)l, 16, 0, 0);
}

// ---- pre-kernel 1: bucket-sort queries by tile count (desc); vl==0 -> NT (full pass = exact mean) ----
__global__ void build_perm(const int* __restrict__ vlg, int* __restrict__ perm) {
    const int b = blockIdx.x, tid = threadIdx.x;
    __shared__ int hist[NT + 1];
    __shared__ int base[NT + 1];
    if (tid <= NT) hist[tid] = 0;
    __syncthreads();
    for (int q = tid; q < LSEQ; q += 256) {
        int vl = vlg[b * LSEQ + q];
        int t = (vl == 0) ? NT : ((vl + KVB - 1) >> 6);
        atomicAdd(&hist[t], 1);
    }
    __syncthreads();
    if (tid == 0) {
        int acc = 0;
        for (int t = NT; t >= 0; --t) { base[t] = acc; acc += hist[t]; }
    }
    __syncthreads();
    for (int q = tid; q < LSEQ; q += 256) {
        int vl = vlg[b * LSEQ + q];
        int t = (vl == 0) ? NT : ((vl + KVB - 1) >> 6);
        int pos = atomicAdd(&base[t], 1);
        perm[b * LSEQ + pos] = q;
    }
}

// ---- pre-kernel 2: K,V -> f16 with XOR swizzle pre-applied (col ^= (row&7)*8), V transposed ----
// K16[bt][row][col^swz]  row=key, col=d     (64x64 f16 = 8KB per tile)
// V16[bt][dv ][key^swz]  row=dv,  col=key   (transposed)
__global__ __launch_bounds__(256) void kvprep(
    const float* __restrict__ kg, const float* __restrict__ vg,
    f16* __restrict__ k16, f16* __restrict__ v16)
{
    const int bt = blockIdx.x;       // b*NT + t
    const int b = bt >> 5, t = bt & 31;
    const int tid = threadIdx.x;
    const float* kb_ = kg + ((size_t)b * LSEQ + t * KVB) * DIM;
    const float* vb_ = vg + ((size_t)b * LSEQ + t * KVB) * DIM;
    f16* kd = k16 + (size_t)bt * (KVB * DIM);
    f16* vd = v16 + (size_t)bt * (KVB * DIM);
#pragma unroll
    for (int it = 0; it < 4; ++it) {
        int cc = tid + it * 256;
        int row = cc >> 4, c4 = (cc & 15) * 4;
        f32x4 x = *(const f32x4*)(kb_ + row * DIM + c4);
        *(f16x4*)(kd + row * 64 + (c4 ^ ((row & 7) * 8))) = pkcvt(x);
    }
    {
        int kb4 = tid & 15, dvb = tid >> 4;
        f32x4 rr[4];
#pragma unroll
        for (int i = 0; i < 4; ++i)
            rr[i] = *(const f32x4*)(vb_ + (size_t)(kb4 * 4 + i) * DIM + dvb * 4);
#pragma unroll
        for (int j = 0; j < 4; ++j) {
            int dv = dvb * 4 + j;
            f32x4 col = {rr[0][j], rr[1][j], rr[2][j], rr[3][j]};
            *(f16x4*)(vd + dv * 64 + ((kb4 * 4) ^ ((dv & 7) * 8))) = pkcvt(col);
        }
    }
}

// ---- main attention kernel: tasks = (qt, b, split); global_load_lds pipeline ----
__global__ __launch_bounds__(256, 3) void attn_fwd(
    const float* __restrict__ qg, const int* __restrict__ vlg,
    const f16* __restrict__ k16, const f16* __restrict__ v16,
    float* __restrict__ outg, const int* __restrict__ perm,
    f16* __restrict__ opart, float* __restrict__ mlg, int S)
{
    __shared__ alignas(16) f16 kbuf[2][KVB * 64];   // 8KB each, swizzled K tile
    __shared__ alignas(16) f16 vbuf[2][DIM * 64];   // 8KB each, swizzled V^T tile
    __shared__ alignas(16) f16 pld[4 * 16 * PITCH]; // per-wave P
    __shared__ int wmax[4];

    const int tid  = threadIdx.x;
    const int wid  = tid >> 6;
    const int lane = tid & 63;
    const int r    = lane & 15;
    const int hi   = lane >> 4;

    const int bid = blockIdx.x;
    const int nbs = NB * S;
    const int qt  = bid / nbs;          // heavy q-tiles first
    const int rem = bid - qt * nbs;
    const int b   = rem / S;
    const int s   = rem - b * S;
    const int qw  = qt * QT + wid * 16;

    const int qidx = perm[b * LSEQ + qw + r];
    const int vl   = vlg[b * LSEQ + qidx];

    int tq = (vl == 0) ? NT : ((vl + KVB - 1) >> 6);
    tq = max(tq, __shfl_xor(tq, 1));
    tq = max(tq, __shfl_xor(tq, 2));
    tq = max(tq, __shfl_xor(tq, 4));
    tq = max(tq, __shfl_xor(tq, 8));
    if (lane == 0) wmax[wid] = tq;
    __syncthreads();
    const int maxt = max(max(wmax[0], wmax[1]), max(wmax[2], wmax[3]));

    int vmin = vl;
    vmin = min(vmin, __shfl_xor(vmin, 1));
    vmin = min(vmin, __shfl_xor(vmin, 2));
    vmin = min(vmin, __shfl_xor(vmin, 4));
    vmin = min(vmin, __shfl_xor(vmin, 8));

    // Q fragments (f32*LOG2E -> f16)
    f16x8 qf[2];
    const float* qrow = qg + ((size_t)(b * LSEQ + qidx)) * DIM;
#pragma unroll
    for (int ks = 0; ks < 2; ++ks) {
        f32x4 x = *(const f32x4*)(qrow + ks * 32 + hi * 8);
        f32x4 y = *(const f32x4*)(qrow + ks * 32 + hi * 8 + 4);
        f32x4 xs = {x[0]*LOG2E, x[1]*LOG2E, x[2]*LOG2E, x[3]*LOG2E};
        f32x4 ys = {y[0]*LOG2E, y[1]*LOG2E, y[2]*LOG2E, y[3]*LOG2E};
        f16x4 lo = pkcvt(xs), hh = pkcvt(ys);
        f16x8 t;
        t[0]=lo[0]; t[1]=lo[1]; t[2]=lo[2]; t[3]=lo[3];
        t[4]=hh[0]; t[5]=hh[1]; t[6]=hh[2]; t[7]=hh[3];
        qf[ks] = t;
    }

    float m_run = -INFINITY;
    float l_run = 0.0f;      // lane-local partial denom
    f32x4 o[4];
#pragma unroll
    for (int dt = 0; dt < 4; ++dt) o[dt] = f32x4{0.f, 0.f, 0.f, 0.f};

    f16* pw = pld + wid * (16 * PITCH);
    const f16* kt_base = k16 + (size_t)b * (NT * KVB * DIM);
    const f16* vt_base = v16 + (size_t)b * (NT * KVB * DIM);
    const int swz = (r & 7) * 8;

    auto stage = [&](int bi, int t) {
        const char* ks = (const char*)(kt_base + (size_t)t * 4096);
        const char* vs = (const char*)(vt_base + (size_t)t * 4096);
        char* kd = (char*)&kbuf[bi][0];
        char* vd = (char*)&vbuf[bi][0];
        gload16(ks + tid * 16,        kd + tid * 16);
        gload16(ks + 4096 + tid * 16, kd + 4096 + tid * 16);
        gload16(vs + tid * 16,        vd + tid * 16);
        gload16(vs + 4096 + tid * 16, vd + 4096 + tid * 16);
    };

    if (s < maxt) stage(0, s);
    int c = 0;
    for (int tt = s; tt < maxt; tt += S) {
        __syncthreads();   // implicit vmcnt(0): my loads landed; everyone done with buf[c^1]
        if (tt + S < maxt) stage(c ^ 1, tt + S);

        // ---- S^T = mfma(K, Q) ----
        f32x4 st[4];
        __builtin_amdgcn_s_setprio(1);
#pragma unroll
        for (int kt = 0; kt < 4; ++kt) {
            f32x4 acc = f32x4{0.f, 0.f, 0.f, 0.f};
#pragma unroll
            for (int ks = 0; ks < 2; ++ks) {
                f16x8 kf = *(const f16x8*)(&kbuf[c][(kt * 16 + r) * 64 + ((ks * 32 + hi * 8) ^ swz)]);
                acc = __builtin_amdgcn_mfma_f32_16x16x32_f16(kf, qf[ks], acc, 0, 0, 0);
            }
            st[kt] = acc;
        }
        __builtin_amdgcn_s_setprio(0);

        // ---- mask (prefix) ----
        const int kv0 = tt * KVB;
        float lanemax = -INFINITY;
        if (kv0 + KVB > vmin) {
#pragma unroll
            for (int kt = 0; kt < 4; ++kt)
#pragma unroll
                for (int g = 0; g < 4; ++g) {
                    int key = kv0 + kt * 16 + hi * 4 + g;
                    float sv = (key < vl) ? st[kt][g] : -1e9f;
                    st[kt][g] = sv;
                    lanemax = fmaxf(lanemax, sv);
                }
        } else {
#pragma unroll
            for (int kt = 0; kt < 4; ++kt)
#pragma unroll
                for (int g = 0; g < 4; ++g)
                    lanemax = fmaxf(lanemax, st[kt][g]);
        }

        // ---- defer-max: only reduce/rescale when some lane exceeds m+8 ----
        if (__any(lanemax > m_run + 8.0f)) {
            float tmax = lanemax;
            tmax = fmaxf(tmax, __shfl_xor(tmax, 16));
            tmax = fmaxf(tmax, __shfl_xor(tmax, 32));
            float m_new = fmaxf(m_run, tmax);
            float scale = exp2f(m_run - m_new);   // first tile: exp2(-inf)=0
            l_run *= scale;
            m_run = m_new;
#pragma unroll
            for (int g = 0; g < 4; ++g) {
                float sc = __shfl(scale, hi * 4 + g);
#pragma unroll
                for (int dt = 0; dt < 4; ++dt) o[dt][g] *= sc;
            }
        }

        // ---- P = exp2(S - m), lane-local l ----
#pragma unroll
        for (int kt = 0; kt < 4; ++kt) {
            f16x4 pv;
#pragma unroll
            for (int g = 0; g < 4; ++g) {
                float p = exp2f(st[kt][g] - m_run);
                l_run += p;
                pv[g] = (f16)p;
            }
            *(f16x4*)(pw + r * PITCH + kt * 16 + hi * 4) = pv;
        }

        // ---- PV ----
        __builtin_amdgcn_s_setprio(1);
#pragma unroll
        for (int ks = 0; ks < 2; ++ks) {
            f16x8 pa = *(const f16x8*)(pw + r * PITCH + ks * 32 + hi * 8);
#pragma unroll
            for (int dt = 0; dt < 4; ++dt) {
                f16x8 vf = *(const f16x8*)(&vbuf[c][(dt * 16 + r) * 64 + ((ks * 32 + hi * 8) ^ swz)]);
                o[dt] = __builtin_amdgcn_mfma_f32_16x16x32_f16(pa, vf, o[dt], 0, 0, 0);
            }
        }
        __builtin_amdgcn_s_setprio(0);
        c ^= 1;
    }

    // ---- epilogue: reduce lane-local l across the 4-lane group ----
    l_run += __shfl_xor(l_run, 16);
    l_run += __shfl_xor(l_run, 32);

    if (S == 1) {
        float inv = 1.0f / l_run;
#pragma unroll
        for (int g = 0; g < 4; ++g) {
            float iv = __shfl(inv, hi * 4 + g);
            int   qo = __shfl(qidx, hi * 4 + g);
            float* ob = outg + ((size_t)(b * LSEQ + qo)) * DIM;
#pragma unroll
            for (int dt = 0; dt < 4; ++dt)
                ob[dt * 16 + r] = o[dt][g] * iv;
        }
    } else {
        f16* obase = opart + ((size_t)s * NB * LSEQ + (size_t)b * LSEQ) * DIM;
#pragma unroll
        for (int g = 0; g < 4; ++g) {
            int qo = __shfl(qidx, hi * 4 + g);
            f16* ob = obase + (size_t)qo * DIM;
#pragma unroll
            for (int dt = 0; dt < 4; ++dt)
                ob[dt * 16 + r] = (f16)o[dt][g];
        }
        if (hi == 0) {
            size_t mi = ((size_t)s * NB * LSEQ + (size_t)b * LSEQ + qidx) * 2;
            mlg[mi]     = m_run;
            mlg[mi + 1] = l_run;
        }
    }
}

// ---- merge kernel: combine S online-softmax partials exactly (opart in f16) ----
__global__ void merge_k(const f16* __restrict__ opart, const float* __restrict__ mlg,
                        float* __restrict__ outg, int S)
{
    const int gt = blockIdx.x * 256 + threadIdx.x;
    const size_t base = (size_t)gt * 4;
    const size_t qg = base >> 6;
    float M = -INFINITY;
    for (int s = 0; s < S; ++s)
        M = fmaxf(M, mlg[((size_t)s * NB * LSEQ + qg) * 2]);
    float den = 0.f;
    f32x4 acc = {0.f, 0.f, 0.f, 0.f};
    for (int s = 0; s < S; ++s) {
        size_t mi = ((size_t)s * NB * LSEQ + qg) * 2;
        float w = exp2f(mlg[mi] - M);   // empty/fully-deferred splits -> w=0
        den += w * mlg[mi + 1];
        f16x4 ov = *(const f16x4*)(opart + (size_t)s * (NB * LSEQ * DIM) + base);
        acc[0] += w * (float)ov[0]; acc[1] += w * (float)ov[1];
        acc[2] += w * (float)ov[2]; acc[3] += w * (float)ov[3];
    }
    float inv = 1.0f / den;
    f32x4 res = {acc[0]*inv, acc[1]*inv, acc[2]*inv, acc[3]*inv};
    *(f32x4*)(outg + base) = res;
}

extern "C" void kernel_launch(void* const* d_in, const int* in_sizes, int n_in,
                              void* d_out, int out_size, void* d_ws, size_t ws_size,
                              hipStream_t stream) {
    const float* q  = (const float*)d_in[0];
    const float* k  = (const float*)d_in[1];
    const float* v  = (const float*)d_in[2];
    const int*   vl = (const int*)d_in[3];
    float* out = (float*)d_out;

    const size_t perm_b = (size_t)NB * LSEQ * sizeof(int);          // 128 KB
    const size_t kv_b   = (size_t)NB * LSEQ * DIM * sizeof(f16);    // 4 MB each
    auto need = [&](int S) {
        return perm_b + 2 * kv_b
             + (size_t)S * NB * LSEQ * 2 * sizeof(float)            // m,l
             + (size_t)S * NB * LSEQ * DIM * sizeof(f16);           // opart f16
    };
    int S;
    if      (ws_size >= need(4)) S = 4;
    else if (ws_size >= need(2)) S = 2;
    else                         S = 1;

    int*   perm  = (int*)d_ws;
    f16*   k16   = (f16*)((char*)d_ws + perm_b);
    f16*   v16   = (f16*)((char*)d_ws + perm_b + kv_b);
    float* mlg   = (float*)((char*)d_ws + perm_b + 2 * kv_b);
    f16*   opart = (f16*)((char*)d_ws + perm_b + 2 * kv_b
                          + (size_t)S * NB * LSEQ * 2 * sizeof(float));

    build_perm<<<NB, 256, 0, stream>>>(vl, perm);
    kvprep<<<NB * NT, 256, 0, stream>>>(k, v, k16, v16);

    attn_fwd<<<dim3(NB * (LSEQ / QT) * S), dim3(256), 0, stream>>>(
        q, vl, k16, v16, out, perm, opart, mlg, S);

    if (S > 1) {
        const int mthreads = NB * LSEQ * DIM / 4;
        merge_k<<<dim3(mthreads / 256), dim3(256), 0, stream>>>(opart, mlg, out, S);
    }
}

// Round 13
// 51.161 us; speedup vs baseline: 1.5797x; 1.0150x over previous
//
#include <hip/hip_runtime.h>

typedef _Float16 f16;
typedef __attribute__((ext_vector_type(8))) _Float16 f16x8;
typedef __attribute__((ext_vector_type(4))) _Float16 f16x4;
typedef __attribute__((ext_vector_type(4))) float f32x4;

#define NB 16
#define LSEQ 2048
#define DIM 64
#define KVB 64
#define QT 128              // queries per block: 4 waves x 2 frags x 16
#define NQT (LSEQ / QT)     // 16
#define NT (LSEQ / KVB)     // 32
#define PITCH 72            // P-buffer pitch (f16): 16B-aligned, spreads banks
#define LOG2E 1.44269504088896340736f

__device__ inline f16x4 pkcvt(const f32x4 x) {
    auto a = __builtin_amdgcn_cvt_pkrtz(x[0], x[1]);
    auto b = __builtin_amdgcn_cvt_pkrtz(x[2], x[3]);
    f16x4 t; t[0]=(f16)a[0]; t[1]=(f16)a[1]; t[2]=(f16)b[0]; t[3]=(f16)b[1];
    return t;
}

__device__ inline void gload16(const void* g, void* l) {
    __builtin_amdgcn_global_load_lds(
        (const __attribute__((address_space(1))) unsigned int*)g,
        (__attribute__((address_space(3))) unsigned int*)l, 16, 0, 0);
}

// ---- fused pre-kernel: blocks 0..511 convert K,V -> f16 (swizzled, V^T); blocks 512.. sort queries ----
__global__ __launch_bounds__(256) void prep(
    const float* __restrict__ kg, const float* __restrict__ vg,
    const int* __restrict__ vlg,
    f16* __restrict__ k16, f16* __restrict__ v16, int* __restrict__ perm)
{
    const int tid = threadIdx.x;
    if (blockIdx.x < NB * NT) {
        const int bt = blockIdx.x;
        const int b = bt >> 5, t = bt & 31;
        const float* kb_ = kg + ((size_t)b * LSEQ + t * KVB) * DIM;
        const float* vb_ = vg + ((size_t)b * LSEQ + t * KVB) * DIM;
        f16* kd = k16 + (size_t)bt * (KVB * DIM);
        f16* vd = v16 + (size_t)bt * (KVB * DIM);
#pragma unroll
        for (int it = 0; it < 4; ++it) {
            int cc = tid + it * 256;
            int row = cc >> 4, c4 = (cc & 15) * 4;
            f32x4 x = *(const f32x4*)(kb_ + row * DIM + c4);
            *(f16x4*)(kd + row * 64 + (c4 ^ ((row & 7) * 8))) = pkcvt(x);
        }
        int kb4 = tid & 15, dvb = tid >> 4;
        f32x4 rr[4];
#pragma unroll
        for (int i = 0; i < 4; ++i)
            rr[i] = *(const f32x4*)(vb_ + (size_t)(kb4 * 4 + i) * DIM + dvb * 4);
#pragma unroll
        for (int j = 0; j < 4; ++j) {
            int dv = dvb * 4 + j;
            f32x4 col = {rr[0][j], rr[1][j], rr[2][j], rr[3][j]};
            *(f16x4*)(vd + dv * 64 + ((kb4 * 4) ^ ((dv & 7) * 8))) = pkcvt(col);
        }
    } else {
        const int b = blockIdx.x - NB * NT;
        __shared__ int hist[NT + 1];
        __shared__ int base[NT + 1];
        if (tid <= NT) hist[tid] = 0;
        __syncthreads();
        for (int q = tid; q < LSEQ; q += 256) {
            int vl = vlg[b * LSEQ + q];
            int t = (vl == 0) ? NT : ((vl + KVB - 1) >> 6);
            atomicAdd(&hist[t], 1);
        }
        __syncthreads();
        if (tid == 0) {
            int acc = 0;
            for (int t = NT; t >= 0; --t) { base[t] = acc; acc += hist[t]; }
        }
        __syncthreads();
        for (int q = tid; q < LSEQ; q += 256) {
            int vl = vlg[b * LSEQ + q];
            int t = (vl == 0) ? NT : ((vl + KVB - 1) >> 6);
            int pos = atomicAdd(&base[t], 1);
            perm[b * LSEQ + pos] = q;
        }
    }
}

// ---- main attention: tasks = (qt, b, split); 2 query-frags per wave; gload_lds dbuf pipeline ----
__global__ __launch_bounds__(256, 3) void attn_fwd(
    const float* __restrict__ qg, const int* __restrict__ vlg,
    const f16* __restrict__ k16, const f16* __restrict__ v16,
    float* __restrict__ outg, const int* __restrict__ perm,
    f16* __restrict__ opart, float* __restrict__ mlg, int S)
{
    __shared__ alignas(16) f16 kbuf[2][KVB * 64];   // 8KB each, swizzled K tile
    __shared__ alignas(16) f16 vbuf[2][DIM * 64];   // 8KB each, swizzled V^T tile
    __shared__ alignas(16) f16 pld[4 * 16 * PITCH]; // per-wave P (reused by both frags)
    __shared__ int wmax[4];

    const int tid  = threadIdx.x;
    const int wid  = tid >> 6;
    const int lane = tid & 63;
    const int r    = lane & 15;
    const int hi   = lane >> 4;

    const int bid = blockIdx.x;
    const int nbs = NB * S;
    const int qt  = bid / nbs;          // heavy q-chunks first (perm sorted desc)
    const int rem = bid - qt * nbs;
    const int b   = rem / S;
    const int s   = rem - b * S;
    const int qw  = qt * QT + wid * 16;

    const int qidxA = perm[b * LSEQ + qw + r];
    const int qidxB = perm[b * LSEQ + qw + 64 + r];
    const int vlA   = vlg[b * LSEQ + qidxA];
    const int vlB   = vlg[b * LSEQ + qidxB];

    // block tile bound over all 128 queries
    int tq = max((vlA == 0) ? NT : ((vlA + KVB - 1) >> 6),
                 (vlB == 0) ? NT : ((vlB + KVB - 1) >> 6));
    tq = max(tq, __shfl_xor(tq, 1));
    tq = max(tq, __shfl_xor(tq, 2));
    tq = max(tq, __shfl_xor(tq, 4));
    tq = max(tq, __shfl_xor(tq, 8));
    if (lane == 0) wmax[wid] = tq;
    __syncthreads();
    const int maxt = max(max(wmax[0], wmax[1]), max(wmax[2], wmax[3]));

    auto wave_min = [&](int v) {
        v = min(v, __shfl_xor(v, 1));
        v = min(v, __shfl_xor(v, 2));
        v = min(v, __shfl_xor(v, 4));
        v = min(v, __shfl_xor(v, 8));
        return v;
    };
    const int vminA = wave_min(vlA);
    const int vminB = wave_min(vlB);

    // Q fragments (f32*LOG2E -> f16)
    auto load_q = [&](int qidx, f16x8* qf) {
        const float* qrow = qg + ((size_t)(b * LSEQ + qidx)) * DIM;
#pragma unroll
        for (int ks = 0; ks < 2; ++ks) {
            f32x4 x = *(const f32x4*)(qrow + ks * 32 + hi * 8);
            f32x4 y = *(const f32x4*)(qrow + ks * 32 + hi * 8 + 4);
            f32x4 xs = {x[0]*LOG2E, x[1]*LOG2E, x[2]*LOG2E, x[3]*LOG2E};
            f32x4 ys = {y[0]*LOG2E, y[1]*LOG2E, y[2]*LOG2E, y[3]*LOG2E};
            f16x4 lo = pkcvt(xs), hh = pkcvt(ys);
            f16x8 t;
            t[0]=lo[0]; t[1]=lo[1]; t[2]=lo[2]; t[3]=lo[3];
            t[4]=hh[0]; t[5]=hh[1]; t[6]=hh[2]; t[7]=hh[3];
            qf[ks] = t;
        }
    };
    f16x8 qfA[2], qfB[2];
    load_q(qidxA, qfA);
    load_q(qidxB, qfB);

    float mA = -INFINITY, mB = -INFINITY;
    float lA = 0.0f, lB = 0.0f;
    f32x4 oA[4], oB[4];
#pragma unroll
    for (int dt = 0; dt < 4; ++dt) { oA[dt] = f32x4{0,0,0,0}; oB[dt] = f32x4{0,0,0,0}; }

    f16* pw = pld + wid * (16 * PITCH);
    const f16* kt_base = k16 + (size_t)b * (NT * KVB * DIM);
    const f16* vt_base = v16 + (size_t)b * (NT * KVB * DIM);
    const int swz = (r & 7) * 8;

    auto stage = [&](int bi, int t) {
        const char* ks = (const char*)(kt_base + (size_t)t * 4096);
        const char* vs = (const char*)(vt_base + (size_t)t * 4096);
        char* kd = (char*)&kbuf[bi][0];
        char* vd = (char*)&vbuf[bi][0];
        gload16(ks + tid * 16,        kd + tid * 16);
        gload16(ks + 4096 + tid * 16, kd + 4096 + tid * 16);
        gload16(vs + tid * 16,        vd + tid * 16);
        gload16(vs + 4096 + tid * 16, vd + 4096 + tid * 16);
    };

    auto do_frag = [&](const f16x8* qf, int vl, int vmin,
                       float& m_run, float& l_run, f32x4* o,
                       int kv0, const f16* kb_, const f16* vb_) {
        f32x4 st[4];
        __builtin_amdgcn_s_setprio(1);
#pragma unroll
        for (int kt = 0; kt < 4; ++kt) {
            f32x4 acc = f32x4{0,0,0,0};
#pragma unroll
            for (int ks = 0; ks < 2; ++ks) {
                f16x8 kf = *(const f16x8*)(&kb_[(kt * 16 + r) * 64 + ((ks * 32 + hi * 8) ^ swz)]);
                acc = __builtin_amdgcn_mfma_f32_16x16x32_f16(kf, qf[ks], acc, 0, 0, 0);
            }
            st[kt] = acc;
        }
        __builtin_amdgcn_s_setprio(0);

        float lanemax = -INFINITY;
        if (kv0 + KVB > vmin) {
#pragma unroll
            for (int kt = 0; kt < 4; ++kt)
#pragma unroll
                for (int g = 0; g < 4; ++g) {
                    int key = kv0 + kt * 16 + hi * 4 + g;
                    float sv = (key < vl) ? st[kt][g] : -1e9f;
                    st[kt][g] = sv;
                    lanemax = fmaxf(lanemax, sv);
                }
        } else {
#pragma unroll
            for (int kt = 0; kt < 4; ++kt)
#pragma unroll
                for (int g = 0; g < 4; ++g)
                    lanemax = fmaxf(lanemax, st[kt][g]);
        }

        if (__any(lanemax > m_run + 8.0f)) {   // defer-max (T13)
            float tmax = lanemax;
            tmax = fmaxf(tmax, __shfl_xor(tmax, 16));
            tmax = fmaxf(tmax, __shfl_xor(tmax, 32));
            float m_new = fmaxf(m_run, tmax);
            float scale = exp2f(m_run - m_new);
            l_run *= scale;
            m_run = m_new;
#pragma unroll
            for (int g = 0; g < 4; ++g) {
                float sc = __shfl(scale, hi * 4 + g);
#pragma unroll
                for (int dt = 0; dt < 4; ++dt) o[dt][g] *= sc;
            }
        }

#pragma unroll
        for (int kt = 0; kt < 4; ++kt) {
            f16x4 pv;
#pragma unroll
            for (int g = 0; g < 4; ++g) {
                float p = exp2f(st[kt][g] - m_run);
                l_run += p;
                pv[g] = (f16)p;
            }
            *(f16x4*)(pw + r * PITCH + kt * 16 + hi * 4) = pv;
        }

        __builtin_amdgcn_s_setprio(1);
#pragma unroll
        for (int ks = 0; ks < 2; ++ks) {
            f16x8 pa = *(const f16x8*)(pw + r * PITCH + ks * 32 + hi * 8);
#pragma unroll
            for (int dt = 0; dt < 4; ++dt) {
                f16x8 vf = *(const f16x8*)(&vb_[(dt * 16 + r) * 64 + ((ks * 32 + hi * 8) ^ swz)]);
                o[dt] = __builtin_amdgcn_mfma_f32_16x16x32_f16(pa, vf, o[dt], 0, 0, 0);
            }
        }
        __builtin_amdgcn_s_setprio(0);
    };

    if (s < maxt) stage(0, s);
    int c = 0;
    for (int tt = s; tt < maxt; tt += S) {
        __syncthreads();   // implicit vmcnt(0): buf[c] staged; all waves done with buf[c^1]
        if (tt + S < maxt) stage(c ^ 1, tt + S);
        const int kv0 = tt * KVB;
        do_frag(qfA, vlA, vminA, mA, lA, oA, kv0, &kbuf[c][0], &vbuf[c][0]);
        do_frag(qfB, vlB, vminB, mB, lB, oB, kv0, &kbuf[c][0], &vbuf[c][0]);
        c ^= 1;
    }

    // ---- epilogue ----
    auto epi = [&](float m_run, float l_run, f32x4* o, int qidx) {
        l_run += __shfl_xor(l_run, 16);
        l_run += __shfl_xor(l_run, 32);
        if (S == 1) {
            float inv = 1.0f / l_run;
#pragma unroll
            for (int g = 0; g < 4; ++g) {
                float iv = __shfl(inv, hi * 4 + g);
                int   qo = __shfl(qidx, hi * 4 + g);
                float* ob = outg + ((size_t)(b * LSEQ + qo)) * DIM;
#pragma unroll
                for (int dt = 0; dt < 4; ++dt)
                    ob[dt * 16 + r] = o[dt][g] * iv;
            }
        } else {
            f16* obase = opart + ((size_t)s * NB * LSEQ + (size_t)b * LSEQ) * DIM;
#pragma unroll
            for (int g = 0; g < 4; ++g) {
                int qo = __shfl(qidx, hi * 4 + g);
                f16* ob = obase + (size_t)qo * DIM;
#pragma unroll
                for (int dt = 0; dt < 4; ++dt)
                    ob[dt * 16 + r] = (f16)o[dt][g];
            }
            if (hi == 0) {
                size_t mi = ((size_t)s * NB * LSEQ + (size_t)b * LSEQ + qidx) * 2;
                mlg[mi]     = m_run;
                mlg[mi + 1] = l_run;
            }
        }
    };
    epi(mA, lA, oA, qidxA);
    epi(mB, lB, oB, qidxB);
}

// ---- merge kernel: combine S online-softmax partials exactly (opart in f16) ----
__global__ void merge_k(const f16* __restrict__ opart, const float* __restrict__ mlg,
                        float* __restrict__ outg, int S)
{
    const int gt = blockIdx.x * 256 + threadIdx.x;
    const size_t base = (size_t)gt * 4;
    const size_t qg = base >> 6;
    float M = -INFINITY;
    for (int s = 0; s < S; ++s)
        M = fmaxf(M, mlg[((size_t)s * NB * LSEQ + qg) * 2]);
    float den = 0.f;
    f32x4 acc = {0.f, 0.f, 0.f, 0.f};
    for (int s = 0; s < S; ++s) {
        size_t mi = ((size_t)s * NB * LSEQ + qg) * 2;
        float w = exp2f(mlg[mi] - M);   // empty splits -> w=0
        den += w * mlg[mi + 1];
        f16x4 ov = *(const f16x4*)(opart + (size_t)s * (NB * LSEQ * DIM) + base);
        acc[0] += w * (float)ov[0]; acc[1] += w * (float)ov[1];
        acc[2] += w * (float)ov[2]; acc[3] += w * (float)ov[3];
    }
    float inv = 1.0f / den;
    f32x4 res = {acc[0]*inv, acc[1]*inv, acc[2]*inv, acc[3]*inv};
    *(f32x4*)(outg + base) = res;
}

extern "C" void kernel_launch(void* const* d_in, const int* in_sizes, int n_in,
                              void* d_out, int out_size, void* d_ws, size_t ws_size,
                              hipStream_t stream) {
    const float* q  = (const float*)d_in[0];
    const float* k  = (const float*)d_in[1];
    const float* v  = (const float*)d_in[2];
    const int*   vl = (const int*)d_in[3];
    float* out = (float*)d_out;

    const size_t perm_b = (size_t)NB * LSEQ * sizeof(int);          // 128 KB
    const size_t kv_b   = (size_t)NB * LSEQ * DIM * sizeof(f16);    // 4 MB each
    auto need = [&](int S) {
        return perm_b + 2 * kv_b
             + (size_t)S * NB * LSEQ * 2 * sizeof(float)
             + (size_t)S * NB * LSEQ * DIM * sizeof(f16);
    };
    int S;
    if      (ws_size >= need(4)) S = 4;
    else if (ws_size >= need(2)) S = 2;
    else                         S = 1;

    int*   perm  = (int*)d_ws;
    f16*   k16   = (f16*)((char*)d_ws + perm_b);
    f16*   v16   = (f16*)((char*)d_ws + perm_b + kv_b);
    float* mlg   = (float*)((char*)d_ws + perm_b + 2 * kv_b);
    f16*   opart = (f16*)((char*)d_ws + perm_b + 2 * kv_b
                          + (size_t)S * NB * LSEQ * 2 * sizeof(float));

    prep<<<NB * NT + NB, 256, 0, stream>>>(k, v, vl, k16, v16, perm);

    attn_fwd<<<dim3(NQT * NB * S), dim3(256), 0, stream>>>(
        q, vl, k16, v16, out, perm, opart, mlg, S);

    if (S > 1) {
        const int mthreads = NB * LSEQ * DIM / 4;
        merge_k<<<dim3(mthreads / 256), dim3(256), 0, stream>>>(opart, mlg, out, S);
    }
}